// Round 1
// baseline (88.966 us; speedup 1.0000x reference)
//
#include <hip/hip_runtime.h>

// SwitchLinear: out[b] = x[b] @ (W[route[b]] + Wf)^T + bias[route[b]] + bf
// B=4096, IN=OUT=256, E=16.
//
// Strategy:
//  1. Fold Wf into per-expert weights once per call (bf16), fold bf into bias.
//  2. Sort tokens by expert -> grouped GEMM tiles (16 tokens x 256 outs).
//  3. bf16 MFMA (16x16x32) grouped GEMM, operands direct from L2 (no LDS staging).

#define B_TOK 4096
#define IN_F 256
#define OUT_F 256
#define NEXP 16
#define WEL (OUT_F * IN_F)            // 65536 elems per expert weight
#define MAX_TILES (B_TOK / 16 + NEXP) // 272 worst-case tiles

typedef __attribute__((ext_vector_type(8))) short bhalf8;  // 8 bf16 = 4 VGPRs
typedef __attribute__((ext_vector_type(4))) float v4f;     // MFMA accumulator

// ws layout (bytes)
#define WSUM_OFF 0u         // ushort[1048576]  bf16(W[e]+Wf)
#define XBF_OFF 2097152u    // ushort[1048576]  bf16(x)
#define BSUM_OFF 4194304u   // float[4096]      bias+bf
#define STOK_OFF 4210688u   // int[4096]        expert-sorted token ids
#define PART_OFF 4227072u   // int[16*16]       per-block expert histograms
#define META_OFF 4228096u   // int[33]          base[16], cursor[16], ntiles
#define DESC_OFF 4228352u   // int[272*3]       {expert, sorted_start, rows}

__device__ __forceinline__ unsigned short f2bf(float f) {
    unsigned u = __float_as_uint(f);
    u += 0x7FFFu + ((u >> 16) & 1u);  // round-nearest-even
    return (unsigned short)(u >> 16);
}

// Fused: wsum/xbf/bsum conversion + expert histogram.
// blocks 0..511   : wsum (8 elems/thread)
// blocks 512..1023: xbf  (8 elems/thread)
// blocks 1024..1027: bsum (4 elems/thread)
// blocks 1028..1043: histogram (256 tokens/block)
__global__ __launch_bounds__(256) void k_prep(
    const float* __restrict__ x, const int* __restrict__ ridx,
    const float* __restrict__ w, const float* __restrict__ wf,
    const float* __restrict__ bias, const float* __restrict__ bf,
    unsigned short* __restrict__ wsum, unsigned short* __restrict__ xbf,
    float* __restrict__ bsum, int* __restrict__ part) {
    int bid = blockIdx.x;
    int tid = threadIdx.x;
    if (bid < 512) {
        int id = (bid * 256 + tid) * 8;
        const float4 a0 = *(const float4*)(w + id);
        const float4 a1 = *(const float4*)(w + id + 4);
        int fo = id & (WEL - 1);
        const float4 f0 = *(const float4*)(wf + fo);
        const float4 f1 = *(const float4*)(wf + fo + 4);
        bhalf8 v;
        v[0] = (short)f2bf(a0.x + f0.x); v[1] = (short)f2bf(a0.y + f0.y);
        v[2] = (short)f2bf(a0.z + f0.z); v[3] = (short)f2bf(a0.w + f0.w);
        v[4] = (short)f2bf(a1.x + f1.x); v[5] = (short)f2bf(a1.y + f1.y);
        v[6] = (short)f2bf(a1.z + f1.z); v[7] = (short)f2bf(a1.w + f1.w);
        *(bhalf8*)(wsum + id) = v;
    } else if (bid < 1024) {
        int id = ((bid - 512) * 256 + tid) * 8;
        const float4 a0 = *(const float4*)(x + id);
        const float4 a1 = *(const float4*)(x + id + 4);
        bhalf8 v;
        v[0] = (short)f2bf(a0.x); v[1] = (short)f2bf(a0.y);
        v[2] = (short)f2bf(a0.z); v[3] = (short)f2bf(a0.w);
        v[4] = (short)f2bf(a1.x); v[5] = (short)f2bf(a1.y);
        v[6] = (short)f2bf(a1.z); v[7] = (short)f2bf(a1.w);
        *(bhalf8*)(xbf + id) = v;
    } else if (bid < 1028) {
        int id = ((bid - 1024) * 256 + tid) * 4;
        const float4 a = *(const float4*)(bias + id);
        const float4 f = *(const float4*)(bf + (id & (OUT_F - 1)));
        float4 r;
        r.x = a.x + f.x; r.y = a.y + f.y; r.z = a.z + f.z; r.w = a.w + f.w;
        *(float4*)(bsum + id) = r;
    } else {
        __shared__ int h[NEXP];
        if (tid < NEXP) h[tid] = 0;
        __syncthreads();
        int hb = bid - 1028;
        atomicAdd(&h[ridx[hb * 256 + tid]], 1);
        __syncthreads();
        if (tid < NEXP) part[hb * NEXP + tid] = h[tid];
    }
}

// Single block: counts -> bases/cursors -> tile descriptors.
__global__ __launch_bounds__(256) void k_plan(const int* __restrict__ part,
                                              int* __restrict__ meta,
                                              int* __restrict__ desc) {
    __shared__ int counts[NEXP];
    __shared__ int base[NEXP];
    __shared__ int tbase[NEXP + 1];
    int t = threadIdx.x;
    if (t < NEXP) {
        int c = 0;
        for (int b = 0; b < 16; ++b) c += part[b * NEXP + t];
        counts[t] = c;
    }
    __syncthreads();
    if (t == 0) {
        int acc = 0, tb = 0;
        for (int e = 0; e < NEXP; ++e) {
            base[e] = acc;
            tbase[e] = tb;
            meta[e] = acc;       // base
            meta[16 + e] = acc;  // cursor (scatter will advance)
            acc += counts[e];
            tb += (counts[e] + 15) >> 4;
        }
        tbase[NEXP] = tb;
        meta[32] = tb;  // total tiles
    }
    __syncthreads();
    int nt = tbase[NEXP];
    for (int i = t; i < MAX_TILES; i += 256) {
        if (i < nt) {
            int e = 0;
            while (!(i >= tbase[e] && i < tbase[e + 1])) ++e;
            int j = i - tbase[e];
            int rem = counts[e] - j * 16;
            desc[i * 3 + 0] = e;
            desc[i * 3 + 1] = base[e] + j * 16;
            desc[i * 3 + 2] = rem < 16 ? rem : 16;
        }
    }
}

// Scatter token ids into expert-sorted order (order within expert arbitrary).
__global__ __launch_bounds__(256) void k_scatter(const int* __restrict__ ridx,
                                                 int* __restrict__ meta,
                                                 int* __restrict__ stok) {
    __shared__ int lc[NEXP];
    __shared__ int gb[NEXP];
    int t = threadIdx.x;
    if (t < NEXP) lc[t] = 0;
    __syncthreads();
    int tok = blockIdx.x * 256 + t;
    int e = ridx[tok];
    int r = atomicAdd(&lc[e], 1);
    __syncthreads();
    if (t < NEXP) gb[t] = atomicAdd(&meta[16 + t], lc[t]);
    __syncthreads();
    stok[gb[e] + r] = tok;
}

// Grouped GEMM: one block per tile (16 tokens x 256 outs, K=256).
// 4 waves; wave w covers outs [64w, 64w+64) as 4 MFMA n-subtiles.
// A-frag: lane holds x[tok(lane&15)][k0 + (lane>>4)*8 + 0..7]
// B-frag: lane holds wsum[e][m=base_n+(lane&15)][k0 + (lane>>4)*8 + 0..7]
// D: col = lane&15, row = (lane>>4)*4 + reg.
__global__ __launch_bounds__(256) void k_gemm(
    const unsigned short* __restrict__ wsum, const unsigned short* __restrict__ xbf,
    const float* __restrict__ bsum, const int* __restrict__ stok,
    const int* __restrict__ meta, const int* __restrict__ desc,
    float* __restrict__ out) {
    int nt_total = meta[32];
    int t = blockIdx.x;
    if (t >= nt_total) return;
    int e = desc[t * 3 + 0];
    int start = desc[t * 3 + 1];
    int rows = desc[t * 3 + 2];

    __shared__ int stk[16];
    int tid = threadIdx.x;
    if (tid < 16) {
        int i = tid < rows ? tid : rows - 1;  // clamp pads to a valid token
        stk[tid] = stok[start + i];
    }
    __syncthreads();

    int lane = tid & 63;
    int wave = tid >> 6;
    int l15 = lane & 15;
    int quad = lane >> 4;

    const unsigned short* xrow = xbf + stk[l15] * IN_F + quad * 8;
    const unsigned short* wbase =
        wsum + e * WEL + (wave * 64 + l15) * IN_F + quad * 8;

    v4f acc[4];
    #pragma unroll
    for (int n = 0; n < 4; ++n) acc[n] = (v4f){0.f, 0.f, 0.f, 0.f};

    #pragma unroll
    for (int ks = 0; ks < 8; ++ks) {
        bhalf8 a = *(const bhalf8*)(xrow + ks * 32);
        bhalf8 b0 = *(const bhalf8*)(wbase + 0 * 16 * IN_F + ks * 32);
        bhalf8 b1 = *(const bhalf8*)(wbase + 1 * 16 * IN_F + ks * 32);
        bhalf8 b2 = *(const bhalf8*)(wbase + 2 * 16 * IN_F + ks * 32);
        bhalf8 b3 = *(const bhalf8*)(wbase + 3 * 16 * IN_F + ks * 32);
        acc[0] = __builtin_amdgcn_mfma_f32_16x16x32_bf16(a, b0, acc[0], 0, 0, 0);
        acc[1] = __builtin_amdgcn_mfma_f32_16x16x32_bf16(a, b1, acc[1], 0, 0, 0);
        acc[2] = __builtin_amdgcn_mfma_f32_16x16x32_bf16(a, b2, acc[2], 0, 0, 0);
        acc[3] = __builtin_amdgcn_mfma_f32_16x16x32_bf16(a, b3, acc[3], 0, 0, 0);
    }

    #pragma unroll
    for (int n = 0; n < 4; ++n) {
        int m = wave * 64 + n * 16 + l15;
        float bb = bsum[e * OUT_F + m];
        #pragma unroll
        for (int r = 0; r < 4; ++r) {
            int row = quad * 4 + r;
            if (row < rows) out[stk[row] * OUT_F + m] = acc[n][r] + bb;
        }
    }
}

extern "C" void kernel_launch(void* const* d_in, const int* in_sizes, int n_in,
                              void* d_out, int out_size, void* d_ws, size_t ws_size,
                              hipStream_t stream) {
    const float* x = (const float*)d_in[0];
    const int* ridx = (const int*)d_in[1];
    const float* w = (const float*)d_in[2];
    const float* wf = (const float*)d_in[3];
    const float* bias = (const float*)d_in[4];
    const float* bf = (const float*)d_in[5];
    float* out = (float*)d_out;
    char* ws = (char*)d_ws;

    unsigned short* wsum = (unsigned short*)(ws + WSUM_OFF);
    unsigned short* xbf = (unsigned short*)(ws + XBF_OFF);
    float* bsum = (float*)(ws + BSUM_OFF);
    int* stok = (int*)(ws + STOK_OFF);
    int* part = (int*)(ws + PART_OFF);
    int* meta = (int*)(ws + META_OFF);
    int* desc = (int*)(ws + DESC_OFF);

    k_prep<<<1044, 256, 0, stream>>>(x, ridx, w, wf, bias, bf, wsum, xbf, bsum, part);
    k_plan<<<1, 256, 0, stream>>>(part, meta, desc);
    k_scatter<<<16, 256, 0, stream>>>(ridx, meta, stok);
    k_gemm<<<MAX_TILES, 256, 0, stream>>>(wsum, xbf, bsum, stok, meta, desc, out);
}